// Round 1
// baseline (439.686 us; speedup 1.0000x reference)
//
#include <hip/hip_runtime.h>
#include <stdint.h>

// ONNX NonMaxSuppression: B=8, C=16, N=2048, MAX_OUT=100
// One block per (batch, class). Exact-match strategy:
//  - stable descending sort via 64-bit key (score bits flipped for total
//    order, low 32 = 0xFFFFFFFF - idx so ties break by ascending index,
//    matching stable jnp.argsort(-scores))
//  - IoU computed with the reference's exact fp32 op order; strict '>' vs
//    thresholds; IEEE division (no fast-math flags, no fma patterns).

#define NBOX 2048
#define THREADS 256
#define MAX_KEEP 256

__global__ __launch_bounds__(THREADS) void nms_kernel(
    const float* __restrict__ boxes,    // B*N*4  (x1,y1,x2,y2)
    const float* __restrict__ scores,   // B*C*N
    const int* __restrict__ maxOutPtr,  // scalar
    const float* __restrict__ iouThrPtr,
    const float* __restrict__ scoreThrPtr,
    int* __restrict__ out,              // B*C*slots*3 int32
    int B, int C, int slots)
{
  __shared__ unsigned long long skeys[NBOX];           // 16 KB
  __shared__ float sx1[NBOX], sy1[NBOX], sx2[NBOX], sy2[NBOX], sar[NBOX]; // 40 KB
  __shared__ unsigned char supp[NBOX];                 // 2 KB
  __shared__ int Vsh, nextP;
  __shared__ int keptIdx[MAX_KEEP];

  const int tid = threadIdx.x;
  const int bc  = blockIdx.x;
  const int b   = bc / C;
  const int c   = bc % C;
  const float iouT   = iouThrPtr[0];
  const float scoreT = scoreThrPtr[0];
  int mOut = maxOutPtr[0];
  if (mOut > slots) mOut = slots;
  if (mOut > MAX_KEEP) mOut = MAX_KEEP;
  if (mOut < 0) mOut = 0;

  const float* cls = scores + ((size_t)b * C + c) * NBOX;

  if (tid == 0) Vsh = 0;
  __syncthreads();

  // Build sort keys + count valid (score > threshold). Valid entries form a
  // prefix after descending sort, so a plain count suffices.
  int vloc = 0;
  for (int j = tid; j < NBOX; j += THREADS) {
    float s = cls[j];
    unsigned bits = __float_as_uint(s);
    unsigned u = (bits & 0x80000000u) ? ~bits : (bits | 0x80000000u);
    skeys[j] = ((unsigned long long)u << 32) | (unsigned)(0xFFFFFFFFu - (unsigned)j);
    if (s > scoreT) vloc++;
  }
  if (vloc) atomicAdd(&Vsh, vloc);

  // Bitonic sort, descending (keys are unique -> strict total order).
  for (unsigned k = 2; k <= NBOX; k <<= 1) {
    for (unsigned stride = k >> 1; stride > 0; stride >>= 1) {
      __syncthreads();
      for (unsigned i = tid; i < NBOX; i += THREADS) {
        unsigned ixj = i ^ stride;
        if (ixj > i) {
          unsigned long long a = skeys[i], bb = skeys[ixj];
          bool up = ((i & k) == 0);          // descending overall
          bool sw = up ? (a < bb) : (a > bb);
          if (sw) { skeys[i] = bb; skeys[ixj] = a; }
        }
      }
    }
  }
  __syncthreads();

  const int V = Vsh;

  // Gather boxes in sorted order (only the valid prefix matters).
  const float4* bx = (const float4*)boxes + (size_t)b * NBOX;
  for (int j = tid; j < V; j += THREADS) {
    int idx = (int)(0xFFFFFFFFu - (unsigned)skeys[j]);
    float4 f = bx[idx];
    sx1[j] = f.x; sy1[j] = f.y; sx2[j] = f.z; sy2[j] = f.w;
    sar[j] = (f.z - f.x) * (f.w - f.y);      // reference: (x2-x1)*(y2-y1)
    supp[j] = 0;
  }
  __syncthreads();

  // Greedy NMS. cnt/start are uniform across threads.
  int cnt = 0, start = 0;
  while (true) {
    if (tid == 0) nextP = 0x7FFFFFFF;
    __syncthreads();
    // Parallel find of first unsuppressed position >= start.
    for (int j = start + tid; j < V; j += THREADS) {
      if (!supp[j]) { atomicMin(&nextP, j); break; }
      if (nextP < j) break;                  // hint: someone earlier already won
    }
    __syncthreads();
    int p = nextP;
    if (p >= V || cnt >= mOut) break;

    if (tid == 0) keptIdx[cnt] = (int)(0xFFFFFFFFu - (unsigned)skeys[p]);
    float px1 = sx1[p], py1 = sy1[p], px2 = sx2[p], py2 = sy2[p], pa = sar[p];

    // Suppress everything after p with IoU > threshold (reference op order).
    for (int j = p + 1 + tid; j < V; j += THREADS) {
      if (!supp[j]) {
        float iw = fminf(px2, sx2[j]) - fmaxf(px1, sx1[j]);
        float ih = fminf(py2, sy2[j]) - fmaxf(py1, sy1[j]);
        iw = fmaxf(iw, 0.0f);
        ih = fmaxf(ih, 0.0f);
        float inter = iw * ih;
        float iou = inter / (pa + sar[j] - inter);
        if (iou > iouT) supp[j] = 1;
      }
    }
    cnt++;
    start = p + 1;
    __syncthreads();                         // supp visible before next find
  }
  __syncthreads();

  // Emit rows: [b, c, idx] for kept slots, [-1,-1,-1] padding.
  int base = bc * slots * 3;
  for (int s = tid; s < slots; s += THREADS) {
    int v = (s < cnt) ? keptIdx[s] : -1;
    out[base + s * 3 + 0] = (v >= 0) ? b : -1;
    out[base + s * 3 + 1] = (v >= 0) ? c : -1;
    out[base + s * 3 + 2] = v;
  }
}

extern "C" void kernel_launch(void* const* d_in, const int* in_sizes, int n_in,
                              void* d_out, int out_size, void* d_ws, size_t ws_size,
                              hipStream_t stream) {
  const float* boxes  = (const float*)d_in[0];
  const float* scores = (const float*)d_in[1];
  const int*   maxOut = (const int*)d_in[2];
  const float* iouT   = (const float*)d_in[3];
  const float* scoreT = (const float*)d_in[4];
  int* out = (int*)d_out;

  const int N  = NBOX;
  int B = in_sizes[0] / (4 * N);        // 8
  int C = in_sizes[1] / (B * N);        // 16
  int slots = out_size / (B * C * 3);   // 100

  nms_kernel<<<dim3(B * C), dim3(THREADS), 0, stream>>>(
      boxes, scores, maxOut, iouT, scoreT, out, B, C, slots);
}

// Round 2
// 93.713 us; speedup vs baseline: 4.6918x; 4.6918x over previous
//
#include <hip/hip_runtime.h>
#include <stdint.h>

// ONNX NMS: B=8, C=16, N=2048, MAX_OUT=100. One block (1024 thr) per (b,c).
// 1) stable descending sort of 64-bit keys (flipped score bits | inverted idx)
//    via bitonic, exactly one compare-exchange per thread per stage.
// 2) chunked greedy: only the first ~mOut kept positions matter. Per 128-wide
//    chunk: parallel IoU vs prior-kept + intra-chunk 128x128 suppression
//    bitmatrix (column-major), then a single-wave register-only cascade walk.
// IoU uses the reference's exact fp32 op order; strict '>' thresholds.

#define NBOX 2048
#define THREADS 1024
#define CHUNK 128
#define MAXKEEP 256

__global__ __launch_bounds__(THREADS) void nms_kernel(
    const float* __restrict__ boxes,    // B*N*4
    const float* __restrict__ scores,   // B*C*N
    const int* __restrict__ maxOutPtr,
    const float* __restrict__ iouThrPtr,
    const float* __restrict__ scoreThrPtr,
    int* __restrict__ out,              // B*C*slots*3
    int B, int C, int slots)
{
  __shared__ unsigned long long skeys[NBOX];                               // 16 KB
  __shared__ float sx1[NBOX], sy1[NBOX], sx2[NBOX], sy2[NBOX], sar[NBOX]; // 40 KB
  __shared__ unsigned colmask[CHUNK][4];   // bit i of colmask[j]: row i suppresses col j
  __shared__ unsigned char suppPre[CHUNK];
  __shared__ int keptPos[MAXKEEP];
  __shared__ int Vsh, cntSh;

  const int tid  = threadIdx.x;
  const int lane = tid & 63;
  const int wave = tid >> 6;
  const int bc = blockIdx.x;
  const int b = bc / C, c = bc % C;
  const float iouT   = iouThrPtr[0];
  const float scoreT = scoreThrPtr[0];
  int mOut = maxOutPtr[0];
  if (mOut > slots) mOut = slots;
  if (mOut > MAXKEEP) mOut = MAXKEEP;
  if (mOut < 0) mOut = 0;

  const float* cls = scores + ((size_t)b * C + c) * NBOX;
  if (tid == 0) { Vsh = 0; cntSh = 0; }
  __syncthreads();

  // --- keys + valid count (2 elements per thread) ---
  {
    float s0 = cls[tid], s1 = cls[tid + 1024];
    unsigned u0 = __float_as_uint(s0); u0 = (u0 & 0x80000000u) ? ~u0 : (u0 | 0x80000000u);
    unsigned u1 = __float_as_uint(s1); u1 = (u1 & 0x80000000u) ? ~u1 : (u1 | 0x80000000u);
    skeys[tid]        = ((unsigned long long)u0 << 32) | (0xFFFFFFFFu - (unsigned)tid);
    skeys[tid + 1024] = ((unsigned long long)u1 << 32) | (0xFFFFFFFFu - (unsigned)(tid + 1024));
    unsigned long long m0 = __ballot(s0 > scoreT);
    unsigned long long m1 = __ballot(s1 > scoreT);
    if (lane == 0) atomicAdd(&Vsh, __popcll(m0) + __popcll(m1));
  }

  // --- bitonic sort, descending; exactly 1 CE per thread per stage ---
  for (unsigned k = 2; k <= NBOX; k <<= 1) {
    for (unsigned s = k >> 1; s > 0; s >>= 1) {
      __syncthreads();
      unsigned i = ((tid & ~(s - 1)) << 1) | (tid & (s - 1));
      unsigned j = i | s;
      unsigned long long a = skeys[i], bb = skeys[j];
      bool up = ((i & k) == 0);
      bool sw = up ? (a < bb) : (a > bb);
      if (sw) { skeys[i] = bb; skeys[j] = a; }
    }
  }
  __syncthreads();
  const int V = Vsh;

  // --- gather boxes in sorted order for the valid prefix ---
  const float4* bx = (const float4*)boxes + (size_t)b * NBOX;
  for (int p = tid; p < V; p += THREADS) {
    int idx = (int)(0xFFFFFFFFu - (unsigned)skeys[p]);
    float4 f = bx[idx];
    sx1[p] = f.x; sy1[p] = f.y; sx2[p] = f.z; sy2[p] = f.w;
    sar[p] = (f.z - f.x) * (f.w - f.y);
  }
  __syncthreads();

  // --- chunked greedy ---
  int cnt = 0;
  for (int s0 = 0; s0 < V && cnt < mOut; s0 += CHUNK) {
    int clen = V - s0; if (clen > CHUNK) clen = CHUNK;

    if (tid < CHUNK * 4) ((unsigned*)colmask)[tid] = 0;
    if (tid < CHUNK) suppPre[tid] = 0;
    __syncthreads();

    // (a) suppressed-by-prior-kept: pairs (kept k, chunk pos q), 8 k's in parallel
    {
      int qo = tid & (CHUNK - 1);
      int ko = tid >> 7;                    // uniform per wave
      if (qo < clen) {
        int q = s0 + qo;
        float qx1 = sx1[q], qy1 = sy1[q], qx2 = sx2[q], qy2 = sy2[q], qa = sar[q];
        int hit = 0;
        for (int k = ko; k < cnt; k += 8) {
          int kp = keptPos[k];
          float iw = fminf(sx2[kp], qx2) - fmaxf(sx1[kp], qx1);
          float ih = fminf(sy2[kp], qy2) - fmaxf(sy1[kp], qy1);
          iw = fmaxf(iw, 0.0f); ih = fmaxf(ih, 0.0f);
          float inter = iw * ih;
          float iou = inter / (sar[kp] + qa - inter);
          if (iou > iouT) hit = 1;
        }
        if (hit) suppPre[qo] = 1;
      }
    }

    // (b) intra-chunk pairwise (i<j): write column-major suppression bits
    {
      int i = tid & (CHUNK - 1);
      if (i < clen) {
        int ip = s0 + i;
        float ix1 = sx1[ip], iy1 = sy1[ip], ix2 = sx2[ip], iy2 = sy2[ip], ia = sar[ip];
        for (int j = tid >> 7; j < clen; j += 8) {   // j uniform per wave
          if (j <= i) continue;
          int q = s0 + j;
          float iw = fminf(ix2, sx2[q]) - fmaxf(ix1, sx1[q]);
          float ih = fminf(iy2, sy2[q]) - fmaxf(iy1, sy1[q]);
          iw = fmaxf(iw, 0.0f); ih = fmaxf(ih, 0.0f);
          float inter = iw * ih;
          float iou = inter / (ia + sar[q] - inter);
          if (iou > iouT) atomicOr(&colmask[j][i >> 5], 1u << (i & 31));
        }
      }
    }
    __syncthreads();

    // (c) single-wave register-only greedy cascade over the chunk
    if (wave == 0) {
      unsigned a0 = colmask[lane][0], a1 = colmask[lane][1];
      unsigned a2 = colmask[lane][2], a3 = colmask[lane][3];
      unsigned b0 = colmask[lane + 64][0], b1 = colmask[lane + 64][1];
      unsigned b2 = colmask[lane + 64][2], b3 = colmask[lane + 64][3];
      int supA = suppPre[lane];
      int supB = suppPre[lane + 64];
      int cl = cnt;
      for (int r = 0; r < clen && cl < mOut; ++r) {
        int v = (r < 64) ? supA : supB;
        int isSup = __shfl(v, r & 63);
        if (!isSup) {
          if (lane == 0) keptPos[cl] = s0 + r;
          cl++;
          unsigned w = r >> 5, bit = r & 31;
          unsigned av = (w == 0) ? a0 : (w == 1) ? a1 : (w == 2) ? a2 : a3;
          unsigned bv = (w == 0) ? b0 : (w == 1) ? b1 : (w == 2) ? b2 : b3;
          supA |= (av >> bit) & 1;
          supB |= (bv >> bit) & 1;
        }
      }
      if (lane == 0) cntSh = cl;
    }
    __syncthreads();
    cnt = cntSh;
  }

  // --- emit [b, c, idx] rows, -1 padded ---
  int base = bc * slots * 3;
  for (int s = tid; s < slots; s += THREADS) {
    int v = -1;
    if (s < cnt) {
      int p = keptPos[s];
      v = (int)(0xFFFFFFFFu - (unsigned)skeys[p]);
    }
    out[base + s * 3 + 0] = (v >= 0) ? b : -1;
    out[base + s * 3 + 1] = (v >= 0) ? c : -1;
    out[base + s * 3 + 2] = v;
  }
}

extern "C" void kernel_launch(void* const* d_in, const int* in_sizes, int n_in,
                              void* d_out, int out_size, void* d_ws, size_t ws_size,
                              hipStream_t stream) {
  const float* boxes  = (const float*)d_in[0];
  const float* scores = (const float*)d_in[1];
  const int*   maxOut = (const int*)d_in[2];
  const float* iouT   = (const float*)d_in[3];
  const float* scoreT = (const float*)d_in[4];
  int* out = (int*)d_out;

  const int N = NBOX;
  int B = in_sizes[0] / (4 * N);
  int C = in_sizes[1] / (B * N);
  int slots = out_size / (B * C * 3);

  nms_kernel<<<dim3(B * C), dim3(THREADS), 0, stream>>>(
      boxes, scores, maxOut, iouT, scoreT, out, B, C, slots);
}

// Round 3
// 92.846 us; speedup vs baseline: 4.7356x; 1.0093x over previous
//
#include <hip/hip_runtime.h>
#include <stdint.h>

// ONNX NMS: B=8, C=16, N=2048, MAX_OUT=100. One block (1024 thr) per (b,c).
// Sort: hybrid bitonic on 64-bit keys (flipped score bits | inverted idx).
//   Element i = wave*128 + r*64 + lane (2 regs/lane). Strides <=64 run in
//   registers via __shfl_xor (no barriers); only strides >=128 touch LDS.
//   10 LDS stages + ~5 barriers replace the 66-barrier full-LDS network.
// Greedy: chunked 128-wide; parallel IoU vs prior-kept + intra-chunk 128x128
//   suppression bitmatrix, then single-wave register-only cascade.
// IoU uses the reference's exact fp32 op order; strict '>' thresholds.

#define NBOX 2048
#define THREADS 1024
#define CHUNK 128
#define MAXKEEP 256

typedef unsigned long long u64;

// Cross-lane compare-exchange: partner = lane ^ s (same r).
// up == descending region. Lower-index lane keeps max when descending.
__device__ __forceinline__ u64 ce_x(u64 v, int s, bool up, int lane) {
  u64 p = __shfl_xor(v, s, 64);
  bool lower = ((lane & s) == 0);
  u64 mx = v > p ? v : p;
  u64 mn = v > p ? p : v;
  return (up == lower) ? mx : mn;
}

__global__ __launch_bounds__(THREADS) void nms_kernel(
    const float* __restrict__ boxes,    // B*N*4
    const float* __restrict__ scores,   // B*C*N
    const int* __restrict__ maxOutPtr,
    const float* __restrict__ iouThrPtr,
    const float* __restrict__ scoreThrPtr,
    int* __restrict__ out,              // B*C*slots*3
    int B, int C, int slots)
{
  __shared__ u64 skeys[NBOX];                                             // 16 KB
  __shared__ float sx1[NBOX], sy1[NBOX], sx2[NBOX], sy2[NBOX], sar[NBOX]; // 40 KB
  __shared__ unsigned colmask[CHUNK][4];
  __shared__ unsigned char suppPre[CHUNK];
  __shared__ int keptPos[MAXKEEP];
  __shared__ int Vsh, cntSh;

  const int tid  = threadIdx.x;
  const int lane = tid & 63;
  const int w    = tid >> 6;          // wave index, 16 waves
  const int bc = blockIdx.x;
  const int b = bc / C, c = bc % C;
  const float iouT   = iouThrPtr[0];
  const float scoreT = scoreThrPtr[0];
  int mOut = maxOutPtr[0];
  if (mOut > slots) mOut = slots;
  if (mOut > MAXKEEP) mOut = MAXKEEP;
  if (mOut < 0) mOut = 0;

  const float* cls = scores + ((size_t)b * C + c) * NBOX;
  if (tid == 0) { Vsh = 0; cntSh = 0; }

  // --- build keys in registers (element i = w*128 + r*64 + lane) ---
  const int j0 = w * 128 + lane;      // r = 0
  const int j1 = j0 + 64;             // r = 1
  float s0 = cls[j0], s1 = cls[j1];
  unsigned u0 = __float_as_uint(s0); u0 = (u0 & 0x80000000u) ? ~u0 : (u0 | 0x80000000u);
  unsigned u1 = __float_as_uint(s1); u1 = (u1 & 0x80000000u) ? ~u1 : (u1 | 0x80000000u);
  u64 e0 = ((u64)u0 << 32) | (0xFFFFFFFFu - (unsigned)j0);
  u64 e1 = ((u64)u1 << 32) | (0xFFFFFFFFu - (unsigned)j1);
  int pop = __popcll(__ballot(s0 > scoreT)) + __popcll(__ballot(s1 > scoreT));

  // --- wave-local bitonic sort of 128-element runs (no barriers) ---
  #pragma unroll
  for (int k = 2; k <= 64; k <<= 1) {
    #pragma unroll
    for (int s = k >> 1; s >= 1; s >>= 1) {
      bool up0 = ((lane & k) == 0);          // (0*64+lane)&k
      bool up1 = (((64 + lane) & k) == 0);   // (1*64+lane)&k
      e0 = ce_x(e0, s, up0, lane);
      e1 = ce_x(e1, s, up1, lane);
    }
  }
  { // k = 128: direction = wave parity; s=64 is the in-lane r-flip
    bool up = ((w & 1) == 0);
    u64 mx = e0 > e1 ? e0 : e1, mn = e0 > e1 ? e1 : e0;
    e0 = up ? mx : mn; e1 = up ? mn : mx;
    #pragma unroll
    for (int s = 32; s >= 1; s >>= 1) {
      e0 = ce_x(e0, s, up, lane);
      e1 = ce_x(e1, s, up, lane);
    }
  }
  skeys[j0] = e0; skeys[j1] = e1;
  __syncthreads();                           // also orders Vsh init vs atomic
  if (lane == 0) atomicAdd(&Vsh, pop);

  // --- global merges k=256..2048: strides>=128 in LDS, <=64 in registers ---
  for (int k = 256; k <= NBOX; k <<= 1) {
    for (int s = k >> 1; s >= 128; s >>= 1) {
      unsigned i = ((tid & ~(s - 1)) << 1) | (tid & (s - 1));
      unsigned jj = i | (unsigned)s;
      u64 a = skeys[i], bb = skeys[jj];
      bool up = ((i & (unsigned)k) == 0);
      bool sw = up ? (a < bb) : (a > bb);
      if (sw) { skeys[i] = bb; skeys[jj] = a; }
      __syncthreads();
    }
    e0 = skeys[j0]; e1 = skeys[j1];
    bool up = (((unsigned)(w * 128) & (unsigned)k) == 0);  // wave-uniform
    u64 mx = e0 > e1 ? e0 : e1, mn = e0 > e1 ? e1 : e0;    // s = 64 (in-lane)
    e0 = up ? mx : mn; e1 = up ? mn : mx;
    #pragma unroll
    for (int s = 32; s >= 1; s >>= 1) {
      e0 = ce_x(e0, s, up, lane);
      e1 = ce_x(e1, s, up, lane);
    }
    skeys[j0] = e0; skeys[j1] = e1;
    __syncthreads();
  }

  const int V = Vsh;

  // --- gather boxes in sorted order for the valid prefix ---
  const float4* bx = (const float4*)boxes + (size_t)b * NBOX;
  for (int p = tid; p < V; p += THREADS) {
    int idx = (int)(0xFFFFFFFFu - (unsigned)skeys[p]);
    float4 f = bx[idx];
    sx1[p] = f.x; sy1[p] = f.y; sx2[p] = f.z; sy2[p] = f.w;
    sar[p] = (f.z - f.x) * (f.w - f.y);
  }
  __syncthreads();

  // --- chunked greedy ---
  int cnt = 0;
  for (int c0 = 0; c0 < V && cnt < mOut; c0 += CHUNK) {
    int clen = V - c0; if (clen > CHUNK) clen = CHUNK;

    if (tid < CHUNK * 4) ((unsigned*)colmask)[tid] = 0;
    if (tid < CHUNK) suppPre[tid] = 0;
    __syncthreads();

    // (a) suppressed-by-prior-kept
    {
      int qo = tid & (CHUNK - 1);
      int ko = tid >> 7;                     // uniform per wave-pair
      if (qo < clen) {
        int q = c0 + qo;
        float qx1 = sx1[q], qy1 = sy1[q], qx2 = sx2[q], qy2 = sy2[q], qa = sar[q];
        int hit = 0;
        for (int k = ko; k < cnt; k += 8) {
          int kp = keptPos[k];
          float iw = fminf(sx2[kp], qx2) - fmaxf(sx1[kp], qx1);
          float ih = fminf(sy2[kp], qy2) - fmaxf(sy1[kp], qy1);
          iw = fmaxf(iw, 0.0f); ih = fmaxf(ih, 0.0f);
          float inter = iw * ih;
          float iou = inter / (sar[kp] + qa - inter);
          if (iou > iouT) hit = 1;
        }
        if (hit) suppPre[qo] = 1;
      }
    }

    // (b) intra-chunk pairwise (i<j): column-major suppression bits
    {
      int i = tid & (CHUNK - 1);
      if (i < clen) {
        int ip = c0 + i;
        float ix1 = sx1[ip], iy1 = sy1[ip], ix2 = sx2[ip], iy2 = sy2[ip], ia = sar[ip];
        for (int j = tid >> 7; j < clen; j += 8) {
          if (j <= i) continue;
          int q = c0 + j;
          float iw = fminf(ix2, sx2[q]) - fmaxf(ix1, sx1[q]);
          float ih = fminf(iy2, sy2[q]) - fmaxf(iy1, sy1[q]);
          iw = fmaxf(iw, 0.0f); ih = fmaxf(ih, 0.0f);
          float inter = iw * ih;
          float iou = inter / (ia + sar[q] - inter);
          if (iou > iouT) atomicOr(&colmask[j][i >> 5], 1u << (i & 31));
        }
      }
    }
    __syncthreads();

    // (c) single-wave register-only greedy cascade
    if (w == 0) {
      unsigned a0 = colmask[lane][0], a1 = colmask[lane][1];
      unsigned a2 = colmask[lane][2], a3 = colmask[lane][3];
      unsigned b0 = colmask[lane + 64][0], b1 = colmask[lane + 64][1];
      unsigned b2 = colmask[lane + 64][2], b3 = colmask[lane + 64][3];
      int supA = suppPre[lane];
      int supB = suppPre[lane + 64];
      int cl = cnt;
      for (int r = 0; r < clen && cl < mOut; ++r) {
        int v = (r < 64) ? supA : supB;
        int isSup = __shfl(v, r & 63);
        if (!isSup) {
          if (lane == 0) keptPos[cl] = c0 + r;
          cl++;
          unsigned wd = r >> 5, bit = r & 31;
          unsigned av = (wd == 0) ? a0 : (wd == 1) ? a1 : (wd == 2) ? a2 : a3;
          unsigned bv = (wd == 0) ? b0 : (wd == 1) ? b1 : (wd == 2) ? b2 : b3;
          supA |= (av >> bit) & 1;
          supB |= (bv >> bit) & 1;
        }
      }
      if (lane == 0) cntSh = cl;
    }
    __syncthreads();
    cnt = cntSh;
  }

  // --- emit [b, c, idx] rows, -1 padded ---
  int base = bc * slots * 3;
  for (int s = tid; s < slots; s += THREADS) {
    int v = -1;
    if (s < cnt) {
      int p = keptPos[s];
      v = (int)(0xFFFFFFFFu - (unsigned)skeys[p]);
    }
    out[base + s * 3 + 0] = (v >= 0) ? b : -1;
    out[base + s * 3 + 1] = (v >= 0) ? c : -1;
    out[base + s * 3 + 2] = v;
  }
}

extern "C" void kernel_launch(void* const* d_in, const int* in_sizes, int n_in,
                              void* d_out, int out_size, void* d_ws, size_t ws_size,
                              hipStream_t stream) {
  const float* boxes  = (const float*)d_in[0];
  const float* scores = (const float*)d_in[1];
  const int*   maxOut = (const int*)d_in[2];
  const float* iouT   = (const float*)d_in[3];
  const float* scoreT = (const float*)d_in[4];
  int* out = (int*)d_out;

  const int N = NBOX;
  int B = in_sizes[0] / (4 * N);
  int C = in_sizes[1] / (B * N);
  int slots = out_size / (B * C * 3);

  nms_kernel<<<dim3(B * C), dim3(THREADS), 0, stream>>>(
      boxes, scores, maxOut, iouT, scoreT, out, B, C, slots);
}

// Round 4
// 89.565 us; speedup vs baseline: 4.9091x; 1.0366x over previous
//
#include <hip/hip_runtime.h>
#include <stdint.h>

// ONNX NMS: B=8, C=16, N=2048, MAX_OUT=100.
// Two-kernel pipeline (R4): per-SIMD issue volume was the bottleneck (16
// redundant waves/CU, half the CUs idle). Kernel A: 256 blocks x 512 thr sort
// each (b,c)'s two 1024-halves (register bitonic for strides<=64, LDS >=128)
// into d_ws; half 1 stored reversed (ascending) so B's merge input is bitonic.
// Kernel B: 128 blocks x 1024 thr do the single k=2048 merge (4 LDS stages +
// register tail), gather boxes, chunked greedy with a ballot-based register
// cascade (no ds ops in the serial walk), emit.
// Keys: (flipped score bits)<<32 | (0xFFFFFFFF - idx)  -> unique, descending
// sort == stable argsort(-scores). IoU in the reference's exact fp32 op order.

#define NBOX 2048
#define HALF 1024
#define TA 512
#define TB 1024
#define CHUNK 128
#define MAXKEEP 256

typedef unsigned long long u64;

__device__ __forceinline__ unsigned flipf(float s) {
  unsigned b = __float_as_uint(s);
  return (b & 0x80000000u) ? ~b : (b | 0x80000000u);
}

// Cross-lane compare-exchange: partner = lane ^ s. up == descending region;
// lower-index lane keeps max when descending.
__device__ __forceinline__ u64 ce_x(u64 v, int s, bool up, int lane) {
  u64 p = __shfl_xor(v, s, 64);
  bool lower = ((lane & s) == 0);
  u64 mx = v > p ? v : p;
  u64 mn = v > p ? p : v;
  return (up == lower) ? mx : mn;
}

// ---------------- Kernel A: sort one 1024-half of one (b,c) ----------------
__global__ __launch_bounds__(TA) void sort_half_kernel(
    const float* __restrict__ scores, u64* __restrict__ wsKeys, int C)
{
  __shared__ u64 sk[HALF];                 // 8 KB
  const int tid = threadIdx.x, lane = tid & 63, w = tid >> 6;   // 8 waves
  const int bc = blockIdx.x >> 1;
  const int h  = blockIdx.x & 1;
  const float* cls = scores + (size_t)bc * NBOX + h * HALF;

  const int p0 = w * 128 + lane;           // local pos, r=0
  const int p1 = p0 + 64;                  // r=1
  const int g0 = h * HALF + p0, g1 = h * HALF + p1;   // global idx in class
  u64 e0 = ((u64)flipf(cls[p0]) << 32) | (0xFFFFFFFFu - (unsigned)g0);
  u64 e1 = ((u64)flipf(cls[p1]) << 32) | (0xFFFFFFFFu - (unsigned)g1);

  // wave-local bitonic sort of 128-element runs (no barriers)
  #pragma unroll
  for (int k = 2; k <= 64; k <<= 1) {
    #pragma unroll
    for (int s = k >> 1; s >= 1; s >>= 1) {
      bool up0 = ((lane & k) == 0);
      bool up1 = (((64 + lane) & k) == 0);
      e0 = ce_x(e0, s, up0, lane);
      e1 = ce_x(e1, s, up1, lane);
    }
  }
  { // k = 128: direction = wave parity; s=64 is the in-lane r-flip
    bool up = ((w & 1) == 0);
    u64 mx = e0 > e1 ? e0 : e1, mn = e0 > e1 ? e1 : e0;
    e0 = up ? mx : mn; e1 = up ? mn : mx;
    #pragma unroll
    for (int s = 32; s >= 1; s >>= 1) {
      e0 = ce_x(e0, s, up, lane);
      e1 = ce_x(e1, s, up, lane);
    }
  }
  sk[p0] = e0; sk[p1] = e1;
  __syncthreads();

  // merges k=256..1024: strides>=128 in LDS, <=64 in registers
  for (int k = 256; k <= HALF; k <<= 1) {
    for (int s = k >> 1; s >= 128; s >>= 1) {
      unsigned i = ((tid & ~(s - 1)) << 1) | (tid & (s - 1));
      unsigned j = i | (unsigned)s;
      u64 a = sk[i], bb = sk[j];
      bool up = ((i & (unsigned)k) == 0);
      bool sw = up ? (a < bb) : (a > bb);
      if (sw) { sk[i] = bb; sk[j] = a; }
      __syncthreads();
    }
    e0 = sk[p0]; e1 = sk[p1];
    bool up = (((unsigned)p0 & (unsigned)k) == 0);   // wave-uniform
    u64 mx = e0 > e1 ? e0 : e1, mn = e0 > e1 ? e1 : e0;  // s=64 in-lane
    e0 = up ? mx : mn; e1 = up ? mn : mx;
    #pragma unroll
    for (int s = 32; s >= 1; s >>= 1) {
      e0 = ce_x(e0, s, up, lane);
      e1 = ce_x(e1, s, up, lane);
    }
    if (k < HALF) { sk[p0] = e0; sk[p1] = e1; __syncthreads(); }
  }

  // store: h=0 descending as-is; h=1 reversed (ascending) for bitonic merge
  u64* dst = wsKeys + (size_t)bc * NBOX + h * HALF;
  if (h == 0) { dst[p0] = e0; dst[p1] = e1; }
  else        { dst[HALF - 1 - p0] = e0; dst[HALF - 1 - p1] = e1; }
}

// ---------------- Kernel B: merge + greedy NMS + emit ----------------
__global__ __launch_bounds__(TB) void nms_kernel(
    const float* __restrict__ boxes,
    const u64* __restrict__ wsKeys,
    const int* __restrict__ maxOutPtr,
    const float* __restrict__ iouThrPtr,
    const float* __restrict__ scoreThrPtr,
    int* __restrict__ out, int B, int C, int slots)
{
  __shared__ u64 sk[NBOX];                                                // 16 KB
  __shared__ float sx1[NBOX], sy1[NBOX], sx2[NBOX], sy2[NBOX], sar[NBOX]; // 40 KB
  __shared__ unsigned colmask[CHUNK][4];
  __shared__ unsigned char suppPre[CHUNK];
  __shared__ int keptPos[MAXKEEP];
  __shared__ int Vsh, cntSh;

  const int tid = threadIdx.x, lane = tid & 63, w = tid >> 6;   // 16 waves
  const int bc = blockIdx.x;
  const int b = bc / C, c = bc % C;
  const float iouT = iouThrPtr[0];
  const unsigned thrU = flipf(scoreThrPtr[0]);
  int mOut = maxOutPtr[0];
  if (mOut > slots) mOut = slots;
  if (mOut > MAXKEEP) mOut = MAXKEEP;
  if (mOut < 0) mOut = 0;

  if (tid == 0) { Vsh = 0; cntSh = 0; }

  // load the two sorted runs (run1 pre-reversed -> ascending); count valid
  const u64* src = wsKeys + (size_t)bc * NBOX;
  u64 v0 = src[tid], v1 = src[tid + HALF];
  sk[tid] = v0; sk[tid + HALF] = v1;
  int pop = __popcll(__ballot((unsigned)(v0 >> 32) > thrU)) +
            __popcll(__ballot((unsigned)(v1 >> 32) > thrU));
  __syncthreads();
  if (lane == 0) atomicAdd(&Vsh, pop);

  // single k=2048 bitonic merge, descending everywhere
  for (int s = 1024; s >= 128; s >>= 1) {
    unsigned i = ((tid & ~(s - 1)) << 1) | (tid & (s - 1));
    unsigned j = i | (unsigned)s;
    u64 a = sk[i], bb = sk[j];
    if (a < bb) { sk[i] = bb; sk[j] = a; }
    __syncthreads();
  }
  {
    const int j0 = w * 128 + lane, j1 = j0 + 64;
    u64 e0 = sk[j0], e1 = sk[j1];
    u64 mx = e0 > e1 ? e0 : e1, mn = e0 > e1 ? e1 : e0;  // s=64 in-lane
    e0 = mx; e1 = mn;
    #pragma unroll
    for (int s = 32; s >= 1; s >>= 1) {
      e0 = ce_x(e0, s, true, lane);
      e1 = ce_x(e1, s, true, lane);
    }
    sk[j0] = e0; sk[j1] = e1;
  }
  __syncthreads();
  const int V = Vsh;

  // gather boxes in sorted order for the valid prefix
  const float4* bx = (const float4*)boxes + (size_t)b * NBOX;
  for (int p = tid; p < V; p += TB) {
    int idx = (int)(0xFFFFFFFFu - (unsigned)sk[p]);
    float4 f = bx[idx];
    sx1[p] = f.x; sy1[p] = f.y; sx2[p] = f.z; sy2[p] = f.w;
    sar[p] = (f.z - f.x) * (f.w - f.y);
  }
  __syncthreads();

  // chunked greedy
  int cnt = 0;
  for (int c0 = 0; c0 < V && cnt < mOut; c0 += CHUNK) {
    int clen = V - c0; if (clen > CHUNK) clen = CHUNK;

    if (tid < CHUNK * 4) ((unsigned*)colmask)[tid] = 0;
    if (tid < CHUNK) suppPre[tid] = 0;
    __syncthreads();

    // (a) suppressed-by-prior-kept
    {
      int qo = tid & (CHUNK - 1);
      int ko = tid >> 7;
      if (qo < clen) {
        int q = c0 + qo;
        float qx1 = sx1[q], qy1 = sy1[q], qx2 = sx2[q], qy2 = sy2[q], qa = sar[q];
        int hit = 0;
        for (int k = ko; k < cnt; k += 8) {
          int kp = keptPos[k];
          float iw = fminf(sx2[kp], qx2) - fmaxf(sx1[kp], qx1);
          float ih = fminf(sy2[kp], qy2) - fmaxf(sy1[kp], qy1);
          iw = fmaxf(iw, 0.0f); ih = fmaxf(ih, 0.0f);
          float inter = iw * ih;
          float iou = inter / (sar[kp] + qa - inter);
          if (iou > iouT) hit = 1;
        }
        if (hit) suppPre[qo] = 1;
      }
    }

    // (b) intra-chunk pairwise (i<j): column-major suppression bits
    {
      int i = tid & (CHUNK - 1);
      if (i < clen) {
        int ip = c0 + i;
        float ix1 = sx1[ip], iy1 = sy1[ip], ix2 = sx2[ip], iy2 = sy2[ip], ia = sar[ip];
        for (int j = tid >> 7; j < clen; j += 8) {
          if (j <= i) continue;
          int q = c0 + j;
          float iw = fminf(ix2, sx2[q]) - fmaxf(ix1, sx1[q]);
          float ih = fminf(iy2, sy2[q]) - fmaxf(iy1, sy1[q]);
          iw = fmaxf(iw, 0.0f); ih = fmaxf(ih, 0.0f);
          float inter = iw * ih;
          float iou = inter / (ia + sar[q] - inter);
          if (iou > iouT) atomicOr(&colmask[j][i >> 5], 1u << (i & 31));
        }
      }
    }
    __syncthreads();

    // (c) single-wave ballot cascade (no LDS in the serial loop).
    // Greedy order is ascending because sup bits are monotone and we always
    // take the lowest live candidate; colmask stores only i<j bits so a kept
    // row never suppresses itself.
    if (w == 0) {
      unsigned a0 = colmask[lane][0], a1 = colmask[lane][1];
      unsigned b0 = colmask[lane + 64][0], b1 = colmask[lane + 64][1];
      unsigned b2 = colmask[lane + 64][2], b3 = colmask[lane + 64][3];
      bool supA = (lane < clen) ? (suppPre[lane] != 0) : true;
      bool supB = (lane + 64 < clen) ? (suppPre[lane + 64] != 0) : true;
      bool doneA = (lane >= clen);
      bool doneB = (lane + 64 >= clen);
      int cl = cnt;
      // first 64 rows
      while (cl < mOut) {
        u64 cand = __ballot(!doneA && !supA);
        if (!cand) break;
        int r = __ffsll((long long)cand) - 1;
        if (lane == 0) keptPos[cl] = c0 + r;
        cl++;
        if (lane == r) doneA = true;
        unsigned av = (r < 32) ? a0 : a1;
        unsigned bv = (r < 32) ? b0 : b1;
        unsigned bit = (unsigned)r & 31;
        supA = supA || ((av >> bit) & 1);
        supB = supB || ((bv >> bit) & 1);
      }
      // rows 64..127
      while (cl < mOut) {
        u64 cand = __ballot(!doneB && !supB);
        if (!cand) break;
        int r = __ffsll((long long)cand) - 1;    // row = 64 + r
        if (lane == 0) keptPos[cl] = c0 + 64 + r;
        cl++;
        if (lane == r) doneB = true;
        unsigned bv = (r < 32) ? b2 : b3;
        unsigned bit = (unsigned)r & 31;
        supB = supB || ((bv >> bit) & 1);
      }
      if (lane == 0) cntSh = cl;
    }
    __syncthreads();
    cnt = cntSh;
  }

  // emit [b, c, idx] rows, -1 padded
  int base = bc * slots * 3;
  for (int s = tid; s < slots; s += TB) {
    int v = -1;
    if (s < cnt) {
      int p = keptPos[s];
      v = (int)(0xFFFFFFFFu - (unsigned)sk[p]);
    }
    out[base + s * 3 + 0] = (v >= 0) ? b : -1;
    out[base + s * 3 + 1] = (v >= 0) ? c : -1;
    out[base + s * 3 + 2] = v;
  }
}

extern "C" void kernel_launch(void* const* d_in, const int* in_sizes, int n_in,
                              void* d_out, int out_size, void* d_ws, size_t ws_size,
                              hipStream_t stream) {
  const float* boxes  = (const float*)d_in[0];
  const float* scores = (const float*)d_in[1];
  const int*   maxOut = (const int*)d_in[2];
  const float* iouT   = (const float*)d_in[3];
  const float* scoreT = (const float*)d_in[4];
  int* out = (int*)d_out;
  u64* wsKeys = (u64*)d_ws;

  const int N = NBOX;
  int B = in_sizes[0] / (4 * N);
  int C = in_sizes[1] / (B * N);
  int slots = out_size / (B * C * 3);

  sort_half_kernel<<<dim3(B * C * 2), dim3(TA), 0, stream>>>(scores, wsKeys, C);
  nms_kernel<<<dim3(B * C), dim3(TB), 0, stream>>>(
      boxes, wsKeys, maxOut, iouT, scoreT, out, B, C, slots);
}